// Round 7
// baseline (120.004 us; speedup 1.0000x reference)
//
#include <hip/hip_runtime.h>

#define HW      4096      // 64*64
#define W_DIM   64
#define C_IN    256
#define NK      25        // 5x5 taps
#define NQ      112       // kq padded 100 -> 112

typedef __bf16 bf16x4 __attribute__((ext_vector_type(4)));
typedef __bf16 bf16x8 __attribute__((ext_vector_type(8)));
typedef float  f32x4  __attribute__((ext_vector_type(4)));
typedef float  f32x2  __attribute__((ext_vector_type(2)));

static __device__ __forceinline__ unsigned short f2bf(float f) {
    unsigned x = __float_as_uint(f);
    return (unsigned short)((x + 0x7fffu + ((x >> 16) & 1u)) >> 16);   // RNE
}
static __device__ __forceinline__ float bflo2f(unsigned u) { return __uint_as_float(u << 16); }
static __device__ __forceinline__ float bfhi2f(unsigned u) { return __uint_as_float(u & 0xffff0000u); }

// ---------------------------------------------------------------------------
// Kernel 1: MFMA 1x1 compress (blocks 0..255) + wtb weight prep (blocks
// 256..507). Verified r6 version, byte-identical.
__global__ __launch_bounds__(256) void k_compress(const float* __restrict__ x,
        const float* __restrict__ wcomp, const float* __restrict__ bcomp,
        const float* __restrict__ wenc,
        unsigned short* __restrict__ comp, unsigned short* __restrict__ wtb) {
    __shared__ unsigned short As[64 * 260];     // 33,280 B
    __shared__ unsigned short Bs[64 * 260];     // 33,280 B
    __shared__ float sbc[64];
    int b = blockIdx.x;
    int tid = threadIdx.x;
    if (b >= 256) {                             // ---- prep tail: wtb only
        int idx = (b - 256) * 256 + tid;        // 252*256 = 64512 exactly
        int c = idx & 63;
        int t2 = idx >> 6;
        int kq = t2 % NQ;
        int tap = t2 / NQ;
        float v = (kq < 100) ? wenc[(kq * 64 + c) * 9 + tap] : 0.0f;
        wtb[idx] = f2bf(v);
        return;
    }
    int n = b >> 6, p0 = (b & 63) * 64;
    int wv = tid >> 6, lane = tid & 63;
    int l15 = lane & 15, l4 = lane >> 4;
    if (tid < 64) sbc[tid] = bcomp[tid];

    const float* xp = x + (size_t)n * C_IN * HW + p0;
#pragma unroll
    for (int s = 0; s < 32; ++s) {              // A: 128 c-pairs x 64 px
        int cp = s * 4 + wv;                    // wave-uniform c-pair
        float a = xp[(size_t)(2 * cp) * HW + lane];
        float bb = xp[(size_t)(2 * cp + 1) * HW + lane];
        unsigned pk = (unsigned)f2bf(a) | ((unsigned)f2bf(bb) << 16);
        *(unsigned*)(As + lane * 260 + cp * 2) = pk;
    }
    const float2* wf = (const float2*)wcomp;    // B: convert f32 -> packed bf16
#pragma unroll
    for (int s = 0; s < 32; ++s) {              // 64 cc x 128 pair-slots
        int slot = s * 256 + tid;
        int cc = slot >> 7, c2 = slot & 127;
        float2 v = wf[cc * 128 + c2];           // coalesced, 8B-aligned
        unsigned pk = (unsigned)f2bf(v.x) | ((unsigned)f2bf(v.y) << 16);
        *(unsigned*)(Bs + cc * 260 + c2 * 2) = pk;
    }
    __syncthreads();

    f32x4 acc[4];
#pragma unroll
    for (int nt = 0; nt < 4; ++nt) acc[nt] = (f32x4){0.f, 0.f, 0.f, 0.f};
#pragma unroll
    for (int ck = 0; ck < 8; ++ck) {
        int ko = ck * 32 + l4 * 8;              // u16 offset in row
        bf16x4 alo = *(const bf16x4*)(As + (wv * 16 + l15) * 260 + ko);
        bf16x4 ahi = *(const bf16x4*)(As + (wv * 16 + l15) * 260 + ko + 4);
        bf16x8 af = __builtin_shufflevector(alo, ahi, 0, 1, 2, 3, 4, 5, 6, 7);
#pragma unroll
        for (int nt = 0; nt < 4; ++nt) {
            bf16x4 blo = *(const bf16x4*)(Bs + (nt * 16 + l15) * 260 + ko);
            bf16x4 bhi = *(const bf16x4*)(Bs + (nt * 16 + l15) * 260 + ko + 4);
            bf16x8 bfr = __builtin_shufflevector(blo, bhi, 0, 1, 2, 3, 4, 5, 6, 7);
            acc[nt] = __builtin_amdgcn_mfma_f32_16x16x32_bf16(af, bfr, acc[nt], 0, 0, 0);
        }
    }
    unsigned short* op = comp + ((size_t)n * HW + p0 + wv * 16 + l4 * 4) * 64;
#pragma unroll
    for (int reg = 0; reg < 4; ++reg)
#pragma unroll
        for (int nt = 0; nt < 4; ++nt) {
            int cc = nt * 16 + l15;
            op[(size_t)reg * 64 + cc] = f2bf(acc[nt][reg] + sbc[cc]);
        }
}

// ---------------------------------------------------------------------------
// Kernel 2: MFMA 3x3 encoder (64->100) + fused softmax. 8x8 tiles, grid (64,4).
// Round-1 verified version, byte-identical (bf16 mask out).
#define CREC    136
#define SB0     13600                // 100 px * 136
#define BSTRIDE 15232                // 112 * 136
#define EPI_PAD 116
__global__ __launch_bounds__(256) void k_enc(
        const unsigned short* __restrict__ comp,
        const unsigned short* __restrict__ wtb,
        const float* __restrict__ benc,
        unsigned short* __restrict__ mask) {
    __shared__ __align__(16) unsigned char smem[SB0 + 2 * BSTRIDE];   // 44,064 B
    __shared__ float sbias[NQ];
    int n = blockIdx.y, tile = blockIdx.x;
    int h0 = (tile >> 3) * 8, w0 = (tile & 7) * 8;
    int tid = threadIdx.x, wv = tid >> 6, lane = tid & 63;
    int l15 = lane & 15, l4 = lane >> 4;
    if (tid < NQ) sbias[tid] = (tid < 100) ? benc[tid] : 0.0f;

    // stage comp halo: 100 px x 128 B, zero OOB (conv zero-pad)
    const uint4* csrc = (const uint4*)(comp + (size_t)n * HW * 64);
#pragma unroll
    for (int pass = 0; pass < 4; ++pass) {
        int s = pass * 256 + tid;               // 800 slots
        if (s < 800) {
            int px = s >> 3, j = s & 7;
            int gh = h0 + px / 10 - 1, gw = w0 + px % 10 - 1;
            uint4 v = make_uint4(0u, 0u, 0u, 0u);
            if ((unsigned)gh < 64u && (unsigned)gw < 64u)
                v = csrc[(size_t)(gh * 64 + gw) * 8 + j];
            *(uint2*)(smem + px * CREC + j * 16)     = make_uint2(v.x, v.y);
            *(uint2*)(smem + px * CREC + j * 16 + 8) = make_uint2(v.z, v.w);
        }
    }
    // stage B(0) -> buf0; preload B(1) -> regs
    {
        const uint4* bs = (const uint4*)wtb;
#pragma unroll
        for (int pass = 0; pass < 4; ++pass) {
            int s = pass * 256 + tid;           // 896 slots
            if (s < 896) {
                uint4 v = bs[s];
                int kq = s >> 3, j = s & 7;
                *(uint2*)(smem + SB0 + kq * CREC + j * 16)     = make_uint2(v.x, v.y);
                *(uint2*)(smem + SB0 + kq * CREC + j * 16 + 8) = make_uint2(v.z, v.w);
            }
        }
    }
    uint4 pre[4];
    {
        const uint4* bs = (const uint4*)(wtb + (size_t)1 * NQ * 64);
#pragma unroll
        for (int pass = 0; pass < 4; ++pass) {
            int s = pass * 256 + tid;
            if (s < 896) pre[pass] = bs[s];
        }
    }

    f32x4 acc[7];
#pragma unroll
    for (int nt = 0; nt < 7; ++nt) acc[nt] = (f32x4){0.f, 0.f, 0.f, 0.f};
    int r_t = 2 * wv + (l15 >> 3), cl = l15 & 7;

    for (int tap = 0; tap < 9; ++tap) {
        __syncthreads();                        // separates buf reads(t-1) from writes(t+1)
        if (tap < 8) {
            unsigned char* nbuf = smem + SB0 + ((tap + 1) & 1) * BSTRIDE;
#pragma unroll
            for (int pass = 0; pass < 4; ++pass) {
                int s = pass * 256 + tid;
                if (s < 896) {
                    int kq = s >> 3, j = s & 7;
                    *(uint2*)(nbuf + kq * CREC + j * 16)     = make_uint2(pre[pass].x, pre[pass].y);
                    *(uint2*)(nbuf + kq * CREC + j * 16 + 8) = make_uint2(pre[pass].z, pre[pass].w);
                }
            }
            if (tap < 7) {
                const uint4* bs = (const uint4*)(wtb + (size_t)(tap + 2) * NQ * 64);
#pragma unroll
                for (int pass = 0; pass < 4; ++pass) {
                    int s = pass * 256 + tid;
                    if (s < 896) pre[pass] = bs[s];
                }
            }
        }
        int ti = tap / 3, tj = tap % 3;
        int apx = (r_t + ti) * 10 + cl + tj;
        const unsigned char* cbuf = smem + SB0 + (tap & 1) * BSTRIDE;
#pragma unroll
        for (int ck = 0; ck < 2; ++ck) {
            int ko = ck * 64 + l4 * 16;         // byte offset in record
            bf16x4 alo = *(const bf16x4*)(smem + apx * CREC + ko);
            bf16x4 ahi = *(const bf16x4*)(smem + apx * CREC + ko + 8);
            bf16x8 af = __builtin_shufflevector(alo, ahi, 0, 1, 2, 3, 4, 5, 6, 7);
#pragma unroll
            for (int nt = 0; nt < 7; ++nt) {
                bf16x4 blo = *(const bf16x4*)(cbuf + (nt * 16 + l15) * CREC + ko);
                bf16x4 bhi = *(const bf16x4*)(cbuf + (nt * 16 + l15) * CREC + ko + 8);
                bf16x8 bfr = __builtin_shufflevector(blo, bhi, 0, 1, 2, 3, 4, 5, 6, 7);
                acc[nt] = __builtin_amdgcn_mfma_f32_16x16x32_bf16(af, bfr, acc[nt], 0, 0, 0);
            }
        }
    }
    __syncthreads();                            // B buffers dead; epilogue overlays

    float* smE = (float*)(smem + SB0) + (size_t)wv * 16 * EPI_PAD;
    unsigned short* maskn = mask + (size_t)n * HW * 100;
#pragma unroll
    for (int nt = 0; nt < 7; ++nt) {
        f32x4 v = acc[nt];
#pragma unroll
        for (int reg = 0; reg < 4; ++reg)
            smE[(l4 * 4 + reg) * EPI_PAD + nt * 16 + l15] = v[reg];
    }
    {
        int spx = lane >> 2, q = lane & 3;
        float* row = smE + spx * EPI_PAD;
        float v[NK], mx = -1e30f;
#pragma unroll
        for (int k = 0; k < NK; ++k) {
            v[k] = row[4 * k + q] + sbias[4 * k + q];
            mx = fmaxf(mx, v[k]);
        }
        float ssum = 0.f;
#pragma unroll
        for (int k = 0; k < NK; ++k) { v[k] = __expf(v[k] - mx); ssum += v[k]; }
        float inv = 1.0f / ssum;
#pragma unroll
        for (int k = 0; k < NK; ++k) row[4 * k + q] = v[k] * inv;
    }
#pragma unroll
    for (int i = 0; i < 7; ++i) {
        int idx = i * 64 + lane;                // 400 slots
        if (idx < 400) {
            int spx = idx / 25, f4 = idx % 25;
            int rr = 2 * wv + (spx >> 3), cc2 = spx & 7;
            size_t p = (size_t)(h0 + rr) * 64 + (w0 + cc2);
            const float* sp = smE + spx * EPI_PAD + f4 * 4;
            unsigned u0 = (unsigned)f2bf(sp[0]) | ((unsigned)f2bf(sp[1]) << 16);
            unsigned u1 = (unsigned)f2bf(sp[2]) | ((unsigned)f2bf(sp[3]) << 16);
            *(uint2*)(maskn + p * 100 + f4 * 4) = make_uint2(u0, u1);
        }
    }
}

// ---------------------------------------------------------------------------
// Kernel 4: reassembly v7 = r6 verified structure; ONLY change: min-waves
// 6 -> 8 (32 waves/CU). Diagnosis: r6 showed deleting 50 LDS reads/thread
// moved total ~1 us -> not LDS-bound; r4 counters (Occ 52, VALU 22, HBM 16)
// say latency-bound. LDS is 11.5 KB (8 blocks = 92 KB ok); constraint is
// VGPR <= 64 (est ~50; r4 staged variant measured 40). If spills appear,
// revert to 6.
#define XSTR2 20
__global__ __launch_bounds__(256, 8) void k_reassemble(const float* __restrict__ x,
        const unsigned short* __restrict__ mask, float* __restrict__ out) {
    __shared__ __align__(16) float xs[144 * XSTR2];   // 11,520 B
    int flat = blockIdx.x;
    int nf = (flat & 7) * 512 + (flat >> 3);    // XCD-contiguous work ids
    int tile = nf & 63, cg = (nf >> 6) & 15, n = nf >> 10;
    int h0 = (tile >> 3) * 8, w0 = (tile & 7) * 8;
    int tid = threadIdx.x;

    // stage x halo: 12x12 px x 16 c, float2 (gw base even -> pairs never
    // straddle the zero-pad boundary), zero OOB
    const float* xb = x + ((size_t)n * C_IN + cg * 16) * HW;
#pragma unroll
    for (int i = 0; i < 5; ++i) {
        int s = i * 256 + tid;                  // 16c * 12r * 6 pairs = 1152
        if (s < 1152) {
            int c = s / 72, rem = s % 72;
            int r = rem / 6, j = rem % 6;
            int gh = h0 - 2 + r, gw = w0 - 2 + j * 2;
            float2 v = make_float2(0.f, 0.f);
            if ((unsigned)gh < 64u && (unsigned)gw < 64u)
                v = *(const float2*)(xb + (size_t)c * HW + gh * W_DIM + gw);
            int px = r * 12 + j * 2;
            xs[px * XSTR2 + c]       = v.x;
            xs[(px + 1) * XSTR2 + c] = v.y;
        }
    }
    __syncthreads();

    int px = tid & 63, w = tid >> 6;            // lane = out px, wave = 4-ch slice
    int wx = px & 7, hy = px >> 3;
    // own mask row, straight from global (L1/L2-resident within the wave)
    const unsigned short* mrow = mask + (size_t)n * HW * 100
                               + (size_t)((h0 + hy) * W_DIM + (w0 + wx)) * 100;
    f32x4 acc0 = {0.f, 0.f, 0.f, 0.f}, acc1 = {0.f, 0.f, 0.f, 0.f};
    f32x4 acc2 = {0.f, 0.f, 0.f, 0.f}, acc3 = {0.f, 0.f, 0.f, 0.f};
#pragma unroll
    for (int di = 0; di < 5; ++di) {
        uint2 mq0 = *(const uint2*)(mrow + (di * 5 + 0) * 4);
        uint2 mq1 = *(const uint2*)(mrow + (di * 5 + 1) * 4);
        uint2 mq2 = *(const uint2*)(mrow + (di * 5 + 2) * 4);
        uint2 mq3 = *(const uint2*)(mrow + (di * 5 + 3) * 4);
        uint2 mq4 = *(const uint2*)(mrow + (di * 5 + 4) * 4);
#pragma unroll
        for (int dj = 0; dj < 5; ++dj) {
            uint2 mw = (dj == 0) ? mq0 : (dj == 1) ? mq1 : (dj == 2) ? mq2
                     : (dj == 3) ? mq3 : mq4;
            f32x4 xv = *(const f32x4*)(xs + ((hy + di) * 12 + wx + dj) * XSTR2 + w * 4);
            acc0 += xv * bflo2f(mw.x);
            acc1 += xv * bfhi2f(mw.x);
            acc2 += xv * bflo2f(mw.y);
            acc3 += xv * bfhi2f(mw.y);
        }
    }
#pragma unroll
    for (int u = 0; u < 4; ++u) {
        float* ob = out + (((size_t)n * C_IN + cg * 16 + w * 4 + u) * 128 + 2 * (h0 + hy)) * 128
                        + 2 * (w0 + wx);
        *(float2*)(ob)       = make_float2(acc0[u], acc1[u]);
        *(float2*)(ob + 128) = make_float2(acc2[u], acc3[u]);
    }
}

// ---------------------------------------------------------------------------
extern "C" void kernel_launch(void* const* d_in, const int* in_sizes, int n_in,
                              void* d_out, int out_size, void* d_ws, size_t ws_size,
                              hipStream_t stream) {
    const float* x      = (const float*)d_in[0];
    const float* w_comp = (const float*)d_in[1];
    const float* b_comp = (const float*)d_in[2];
    const float* w_enc  = (const float*)d_in[3];
    const float* b_enc  = (const float*)d_in[4];
    float* out = (float*)d_out;
    unsigned char* ws = (unsigned char*)d_ws;

    unsigned short* comp  = (unsigned short*)(ws);             // 4*4096*64*2  = 2,097,152 B
    unsigned short* wtb   = (unsigned short*)(ws + 2097152);   // 9*112*64*2   =   129,024 B
    unsigned short* maskp = (unsigned short*)(ws + 2226176);   // 4*4096*100*2 = 3,276,800 B

    hipLaunchKernelGGL(k_compress,   dim3(508),      dim3(256), 0, stream,
                       x, w_comp, b_comp, w_enc, comp, wtb);
    hipLaunchKernelGGL(k_enc,        dim3(64, 4),    dim3(256), 0, stream,
                       comp, wtb, b_enc, maskp);
    hipLaunchKernelGGL(k_reassemble, dim3(4096),     dim3(256), 0, stream,
                       x, maskp, out);
}